// Round 1
// baseline (322.773 us; speedup 1.0000x reference)
//
#include <hip/hip_runtime.h>
#include <hip/hip_bf16.h>
#include <cstdint>

// Problem: B=128, T=512, F=512, M=512 (all fixed by setup_inputs).
// out[b,m,f] = gelu( sum_t xn[b,t,f]*W[m,t] + bias[m] ) + x[b,m,f]
// xn = layernorm over t per (b,f), * gamma[t] + beta[t].

#define B_ 128
#define T_ 512
#define F_ 512
#define M_ 512
#define FT 32           // f-tile per block
#define XN_STRIDE 520   // bf16 elems per f-row of xnS (512 + 8 pad)

typedef __attribute__((ext_vector_type(8))) short bf16x8;
typedef __attribute__((ext_vector_type(4))) float f32x4;

static __device__ __forceinline__ unsigned short f2bf(float f) {
    // round-to-nearest-even f32 -> bf16 (inputs are finite; no NaN path needed)
    unsigned int u = __float_as_uint(f);
    unsigned int r = u + 0x7FFFu + ((u >> 16) & 1u);
    return (unsigned short)(r >> 16);
}

static __device__ __forceinline__ void gld_lds16(const void* gptr, void* lptr) {
    __builtin_amdgcn_global_load_lds(
        (const __attribute__((address_space(1))) unsigned int*)gptr,
        (__attribute__((address_space(3))) unsigned int*)lptr,
        16, 0, 0);
}

// ---------------- W fp32 -> bf16 convert (runs every launch; ws is re-poisoned) ----
__global__ void wconv_kernel(const float* __restrict__ W, unsigned short* __restrict__ Wb) {
    int i = (blockIdx.x * 256 + threadIdx.x) * 4;
    float4 v = *(const float4*)(W + i);
    ushort4 o;
    o.x = f2bf(v.x); o.y = f2bf(v.y); o.z = f2bf(v.z); o.w = f2bf(v.w);
    *(ushort4*)(Wb + i) = o;
}

// ---------------- fused LN + GEMM + GELU + residual ------------------------------
// grid = (F/FT=16, B=128), block = 512 threads (8 waves)
// LDS layout (bytes):
//   [0,     33280)  xnS  : bf16 [32 f][520 t-stride]   (row stride 1040 B)
//   [33280, 66048)  wS   : bf16 [512 m][32 k]          (row stride 64 B)
//                   red_sum/red_sq alias first 4 KB of wS (used pre-GEMM only)
//   [66048, 68096)  gS   : float[512]  gamma
//   [68096, 70144)  bS   : float[512]  beta
//   [70144, 70272)  meanS: float[32]
//   [70272, 70400)  rstdS: float[32]
// total 70400 B -> 2 blocks/CU.
__global__ __launch_bounds__(512, 4) void timemix_main(
    const float* __restrict__ x, const float* __restrict__ gamma,
    const float* __restrict__ beta, const unsigned short* __restrict__ Wb,
    const float* __restrict__ bias, float* __restrict__ out)
{
    __shared__ __align__(16) unsigned char smem[70400];
    unsigned char* xnS = smem;                         // bf16 [32][520]
    unsigned char* wS  = smem + 33280;                 // bf16 [512][32]
    float* red_sum = (float*)(smem + 33280);           // [16][32] (alias wS)
    float* red_sq  = (float*)(smem + 33280 + 2048);    // [16][32] (alias wS)
    float* gS      = (float*)(smem + 66048);
    float* bS      = (float*)(smem + 68096);
    float* meanS   = (float*)(smem + 70144);
    float* rstdS   = (float*)(smem + 70272);

    const int tid   = threadIdx.x;
    const int w     = tid >> 6;
    const int lane  = tid & 63;
    const int batch = blockIdx.y;
    const int f0    = blockIdx.x * FT;

    // phase 0: stage gamma/beta
    gS[tid] = gamma[tid];
    bS[tid] = beta[tid];

    // phase 1: load 32 consecutive-t values of one f-column; partial stats
    const int f  = lane & 31;
    const int tg = w * 2 + (lane >> 5);       // [0,16): t in [tg*32, tg*32+32)
    float xv[32];
    {
        const float* xb = x + ((size_t)batch * T_ + (size_t)tg * 32) * F_ + f0 + f;
        float s = 0.f, q = 0.f;
        #pragma unroll
        for (int i = 0; i < 32; ++i) {
            float v = xb[(size_t)i * F_];
            xv[i] = v; s += v; q += v * v;
        }
        red_sum[tg * 32 + f] = s;
        red_sq [tg * 32 + f] = q;
    }
    __syncthreads();

    // phase 2: reduce 16 partials per f -> mean/rstd
    if (tid < 32) {
        float s = 0.f, q = 0.f;
        #pragma unroll
        for (int g = 0; g < 16; ++g) { s += red_sum[g * 32 + tid]; q += red_sq[g * 32 + tid]; }
        float mean = s * (1.0f / 512.0f);
        float var  = q * (1.0f / 512.0f) - mean * mean;
        meanS[tid] = mean;
        rstdS[tid] = rsqrtf(var + 1e-5f);
    }
    __syncthreads();

    // phase 3: normalize from fp32 registers, pack bf16, write xnS rows
    {
        const float mean = meanS[f];
        const float rstd = rstdS[f];
        #pragma unroll
        for (int c = 0; c < 4; ++c) {
            const int t0 = tg * 32 + c * 8;
            unsigned int pr[4];
            #pragma unroll
            for (int h = 0; h < 4; ++h) {
                float a0 = rstd * gS[t0 + 2 * h];
                float v0 = xv[c * 8 + 2 * h] * a0 + (bS[t0 + 2 * h] - mean * a0);
                float a1 = rstd * gS[t0 + 2 * h + 1];
                float v1 = xv[c * 8 + 2 * h + 1] * a1 + (bS[t0 + 2 * h + 1] - mean * a1);
                pr[h] = (unsigned int)f2bf(v0) | ((unsigned int)f2bf(v1) << 16);
            }
            uint4 pk; pk.x = pr[0]; pk.y = pr[1]; pk.z = pr[2]; pk.w = pr[3];
            *(uint4*)(xnS + (size_t)f * (XN_STRIDE * 2) + t0 * 2) = pk;
        }
    }
    __syncthreads();  // last block-wide barrier; K-loop is barrier-free

    // GEMM: wave w owns output rows m in [64w, 64w+64), cols f0..f0+31
    const int lr = lane & 15;
    const int q4 = lane >> 4;
    f32x4 acc[4][2];
    #pragma unroll
    for (int mi = 0; mi < 4; ++mi)
        #pragma unroll
        for (int fi = 0; fi < 2; ++fi)
            acc[mi][fi] = (f32x4){0.f, 0.f, 0.f, 0.f};

    const int srow = lane >> 2;   // staging: row within 16-row group
    const int sch  = lane & 3;    // staging: 16B chunk within 64B row

    for (int kc = 0; kc < 16; ++kc) {
        const int k0 = kc * 32;
        __builtin_amdgcn_sched_barrier(0);
        // stage this wave's 64 W rows (wave-private LDS region -> no __syncthreads)
        #pragma unroll
        for (int r = 0; r < 4; ++r) {
            const int m0 = w * 64 + r * 16;                       // wave-uniform
            const void* g = (const void*)(Wb + (size_t)(m0 + srow) * 512 + k0 + sch * 8);
            void* l = (void*)(wS + m0 * 64);
            gld_lds16(g, l);
        }
        __builtin_amdgcn_s_waitcnt(0x0F70);  // vmcnt(0), lgkm/exp don't-care
        __builtin_amdgcn_sched_barrier(0);

        bf16x8 af[4], bfr[2];
        #pragma unroll
        for (int mi = 0; mi < 4; ++mi)
            af[mi] = *(const bf16x8*)(wS + (size_t)(w * 64 + mi * 16 + lr) * 64 + q4 * 16);
        #pragma unroll
        for (int fi = 0; fi < 2; ++fi)
            bfr[fi] = *(const bf16x8*)(xnS + (size_t)(fi * 16 + lr) * (XN_STRIDE * 2) + k0 * 2 + q4 * 16);
        #pragma unroll
        for (int mi = 0; mi < 4; ++mi)
            #pragma unroll
            for (int fi = 0; fi < 2; ++fi)
                acc[mi][fi] = __builtin_amdgcn_mfma_f32_16x16x32_bf16(af[mi], bfr[fi], acc[mi][fi], 0, 0, 0);
    }

    // epilogue: bias + exact gelu + residual
    #pragma unroll
    for (int mi = 0; mi < 4; ++mi) {
        const int mbase = w * 64 + mi * 16 + q4 * 4;
        #pragma unroll
        for (int r = 0; r < 4; ++r) {
            const int m = mbase + r;
            const float bv = bias[m];
            #pragma unroll
            for (int fi = 0; fi < 2; ++fi) {
                float y = acc[mi][fi][r] + bv;
                float gl = 0.5f * y * (1.0f + erff(y * 0.70710678118654752f));
                size_t o = ((size_t)(batch * 512 + m)) * 512 + (size_t)(f0 + fi * 16 + lr);
                out[o] = gl + x[o];
            }
        }
    }
}

extern "C" void kernel_launch(void* const* d_in, const int* in_sizes, int n_in,
                              void* d_out, int out_size, void* d_ws, size_t ws_size,
                              hipStream_t stream) {
    const float* x     = (const float*)d_in[0];
    const float* gamma = (const float*)d_in[1];
    const float* beta  = (const float*)d_in[2];
    const float* W     = (const float*)d_in[3];
    const float* bias  = (const float*)d_in[4];
    float* out = (float*)d_out;
    unsigned short* Wb = (unsigned short*)d_ws;  // 512*512*2 = 512 KB scratch

    wconv_kernel<<<dim3(M_ * T_ / (256 * 4)), 256, 0, stream>>>(W, Wb);
    dim3 grid(F_ / FT, B_);
    timemix_main<<<grid, 512, 0, stream>>>(x, gamma, beta, Wb, bias, out);
}

// Round 2
// 303.810 us; speedup vs baseline: 1.0624x; 1.0624x over previous
//
#include <hip/hip_runtime.h>
#include <hip/hip_bf16.h>
#include <cstdint>

// Problem: B=128, T=512, F=512, M=512 (fixed by setup_inputs).
// out[b,m,f] = gelu( sum_t xn[b,t,f]*W[m,t] + bias[m] ) + x[b,m,f]
// xn = layernorm over t per (b,f), * gamma[t] + beta[t].

#define B_ 128
#define T_ 512
#define F_ 512
#define M_ 512
#define FT 32           // f-tile per block
#define XN_STRIDE 520   // bf16 elems per f-row of xnS (512 + 8 pad -> 2-way (free) LDS reads)

typedef __attribute__((ext_vector_type(8))) short bf16x8;
typedef __attribute__((ext_vector_type(4))) float f32x4;

static __device__ __forceinline__ unsigned short f2bf(float f) {
    unsigned int u = __float_as_uint(f);
    unsigned int r = u + 0x7FFFu + ((u >> 16) & 1u);
    return (unsigned short)(r >> 16);
}

// ---------------- W fp32 -> bf16 convert + fragment-major permute ----------------
// Wq is an array of 16 B chunks indexed [kc(16)][mg(32)][lane(64)]:
//   chunk(kc,mg,lane) = W[m = mg*16 + (lane&15)][k = kc*32 + (lane>>4)*8 .. +8) as bf16
// so an A-fragment load for wave-tile mg at K-chunk kc is ONE fully-coalesced
// 1 KB global_load_dwordx4 (lane i reads base + i*16).
__global__ void wconv_kernel(const float* __restrict__ W, unsigned short* __restrict__ Wq) {
    int idx  = blockIdx.x * 256 + threadIdx.x;   // one 16 B chunk per thread; 32768 total
    int lane = idx & 63;
    int mg   = (idx >> 6) & 31;
    int kc   = idx >> 11;
    int m = mg * 16 + (lane & 15);
    int k = kc * 32 + (lane >> 4) * 8;
    const float* src = W + (size_t)m * 512 + k;
    float4 v0 = *(const float4*)(src);
    float4 v1 = *(const float4*)(src + 4);
    uint4 o;
    o.x = (unsigned int)f2bf(v0.x) | ((unsigned int)f2bf(v0.y) << 16);
    o.y = (unsigned int)f2bf(v0.z) | ((unsigned int)f2bf(v0.w) << 16);
    o.z = (unsigned int)f2bf(v1.x) | ((unsigned int)f2bf(v1.y) << 16);
    o.w = (unsigned int)f2bf(v1.z) | ((unsigned int)f2bf(v1.w) << 16);
    *(uint4*)(Wq + (size_t)idx * 8) = o;
}

// ---------------- fused LN + GEMM + GELU + residual ------------------------------
// grid = (F/FT=16, B=128), block = 512 threads (8 waves)
// LDS (37632 B total -> not the occupancy limiter; VGPR<=128 -> 2 blocks/CU, 16 waves/CU):
//   [0,     33280)  xnS  : bf16 [32 f][520 t-stride]
//   [33280, 35328)  gS   : float[512] gamma
//   [35328, 37376)  bS   : float[512] beta
//   [37376, 37504)  meanS: float[32]
//   [37504, 37632)  rstdS: float[32]
__global__ __launch_bounds__(512, 4) void timemix_main(
    const float* __restrict__ x, const float* __restrict__ gamma,
    const float* __restrict__ beta, const unsigned short* __restrict__ Wq,
    const float* __restrict__ bias, float* __restrict__ out)
{
    __shared__ __align__(16) unsigned char smem[37632];
    unsigned char* xnS = smem;                      // bf16 [32][520]
    float* gS    = (float*)(smem + 33280);
    float* bS    = (float*)(smem + 35328);
    float* meanS = (float*)(smem + 37376);
    float* rstdS = (float*)(smem + 37504);
    __shared__ float red_sum[16 * 32];
    __shared__ float red_sq[16 * 32];

    const int tid   = threadIdx.x;
    const int w     = tid >> 6;
    const int lane  = tid & 63;
    const int batch = blockIdx.y;
    const int f0    = blockIdx.x * FT;

    // phase 0: stage gamma/beta
    gS[tid] = gamma[tid];
    bS[tid] = beta[tid];

    // phase 1: each thread loads 32 consecutive-t values of one f-column (coalesced
    // 128 B per 32-lane group); partial sum/sumsq
    const int f  = lane & 31;
    const int tg = w * 2 + (lane >> 5);             // [0,16): t in [tg*32, tg*32+32)
    float xv[32];
    {
        const float* xb = x + ((size_t)batch * T_ + (size_t)tg * 32) * F_ + f0 + f;
        float s = 0.f, q = 0.f;
        #pragma unroll
        for (int i = 0; i < 32; ++i) {
            float v = xb[(size_t)i * F_];
            xv[i] = v; s += v; q += v * v;
        }
        red_sum[tg * 32 + f] = s;
        red_sq [tg * 32 + f] = q;
    }
    __syncthreads();

    // phase 2: reduce 16 partials per f -> mean/rstd
    if (tid < 32) {
        float s = 0.f, q = 0.f;
        #pragma unroll
        for (int g = 0; g < 16; ++g) { s += red_sum[g * 32 + tid]; q += red_sq[g * 32 + tid]; }
        float mean = s * (1.0f / 512.0f);
        float var  = q * (1.0f / 512.0f) - mean * mean;
        meanS[tid] = mean;
        rstdS[tid] = rsqrtf(var + 1e-5f);
    }
    __syncthreads();

    // phase 3: normalize from fp32 registers, pack bf16, write xnS rows
    {
        const float mean = meanS[f];
        const float rstd = rstdS[f];
        #pragma unroll
        for (int c = 0; c < 4; ++c) {
            const int t0 = tg * 32 + c * 8;
            unsigned int pr[4];
            #pragma unroll
            for (int h = 0; h < 4; ++h) {
                float a0 = rstd * gS[t0 + 2 * h];
                float v0 = xv[c * 8 + 2 * h] * a0 + (bS[t0 + 2 * h] - mean * a0);
                float a1 = rstd * gS[t0 + 2 * h + 1];
                float v1 = xv[c * 8 + 2 * h + 1] * a1 + (bS[t0 + 2 * h + 1] - mean * a1);
                pr[h] = (unsigned int)f2bf(v0) | ((unsigned int)f2bf(v1) << 16);
            }
            uint4 pk; pk.x = pr[0]; pk.y = pr[1]; pk.z = pr[2]; pk.w = pr[3];
            *(uint4*)(xnS + (size_t)f * (XN_STRIDE * 2) + t0 * 2) = pk;
        }
    }
    __syncthreads();  // last barrier; K-loop is barrier-free

    // GEMM: wave w owns output rows m in [64w, 64w+64), cols f0..f0+31.
    // A-fragments come straight from Wq (register double-buffer, prefetch depth 1
    // -> loads stay in flight across MFMAs, no vmcnt(0) stall).
    const int lr = lane & 15;
    const int q4 = lane >> 4;
    const unsigned short* wbase = Wq + ((size_t)(w * 4) * 64 + lane) * 8;
    // +kc*16384 elems per K-chunk, +mi*512 elems per m-tile

    f32x4 acc[4][2];
    #pragma unroll
    for (int mi = 0; mi < 4; ++mi)
        #pragma unroll
        for (int fi = 0; fi < 2; ++fi)
            acc[mi][fi] = (f32x4){0.f, 0.f, 0.f, 0.f};

    bf16x8 aA[4], aB[4];
    #pragma unroll
    for (int mi = 0; mi < 4; ++mi)
        aA[mi] = *(const bf16x8*)(wbase + (size_t)mi * 512);

    for (int kc = 0; kc < 16; kc += 2) {
        // prefetch kc+1 (kc+1 <= 15 always)
        #pragma unroll
        for (int mi = 0; mi < 4; ++mi)
            aB[mi] = *(const bf16x8*)(wbase + (size_t)(kc + 1) * 16384 + (size_t)mi * 512);
        {
            bf16x8 b0 = *(const bf16x8*)(xnS + (size_t)lr * (XN_STRIDE * 2) + kc * 64 + q4 * 16);
            bf16x8 b1 = *(const bf16x8*)(xnS + (size_t)(16 + lr) * (XN_STRIDE * 2) + kc * 64 + q4 * 16);
            #pragma unroll
            for (int mi = 0; mi < 4; ++mi) {
                acc[mi][0] = __builtin_amdgcn_mfma_f32_16x16x32_bf16(aA[mi], b0, acc[mi][0], 0, 0, 0);
                acc[mi][1] = __builtin_amdgcn_mfma_f32_16x16x32_bf16(aA[mi], b1, acc[mi][1], 0, 0, 0);
            }
        }
        // prefetch kc+2
        if (kc + 2 < 16) {
            #pragma unroll
            for (int mi = 0; mi < 4; ++mi)
                aA[mi] = *(const bf16x8*)(wbase + (size_t)(kc + 2) * 16384 + (size_t)mi * 512);
        }
        {
            bf16x8 b0 = *(const bf16x8*)(xnS + (size_t)lr * (XN_STRIDE * 2) + (kc + 1) * 64 + q4 * 16);
            bf16x8 b1 = *(const bf16x8*)(xnS + (size_t)(16 + lr) * (XN_STRIDE * 2) + (kc + 1) * 64 + q4 * 16);
            #pragma unroll
            for (int mi = 0; mi < 4; ++mi) {
                acc[mi][0] = __builtin_amdgcn_mfma_f32_16x16x32_bf16(aB[mi], b0, acc[mi][0], 0, 0, 0);
                acc[mi][1] = __builtin_amdgcn_mfma_f32_16x16x32_bf16(aB[mi], b1, acc[mi][1], 0, 0, 0);
            }
        }
    }

    // epilogue: bias + exact gelu + residual (x re-read expected L3-resident)
    #pragma unroll
    for (int mi = 0; mi < 4; ++mi) {
        const int mbase = w * 64 + mi * 16 + q4 * 4;
        #pragma unroll
        for (int r = 0; r < 4; ++r) {
            const int m = mbase + r;
            const float bv = bias[m];
            #pragma unroll
            for (int fi = 0; fi < 2; ++fi) {
                float y = acc[mi][fi][r] + bv;
                float gl = 0.5f * y * (1.0f + erff(y * 0.70710678118654752f));
                size_t o = ((size_t)(batch * 512 + m)) * 512 + (size_t)(f0 + fi * 16 + lr);
                out[o] = gl + x[o];
            }
        }
    }
}

extern "C" void kernel_launch(void* const* d_in, const int* in_sizes, int n_in,
                              void* d_out, int out_size, void* d_ws, size_t ws_size,
                              hipStream_t stream) {
    const float* x     = (const float*)d_in[0];
    const float* gamma = (const float*)d_in[1];
    const float* beta  = (const float*)d_in[2];
    const float* W     = (const float*)d_in[3];
    const float* bias  = (const float*)d_in[4];
    float* out = (float*)d_out;
    unsigned short* Wq = (unsigned short*)d_ws;  // 512 KB fragment-major bf16 W

    wconv_kernel<<<dim3(128), 256, 0, stream>>>(W, Wq);
    dim3 grid(F_ / FT, B_);
    timemix_main<<<grid, 512, 0, stream>>>(x, gamma, beta, Wq, bias, out);
}